// Round 1
// baseline (1162.573 us; speedup 1.0000x reference)
//
#include <hip/hip_runtime.h>
#include <hip/hip_bf16.h>
#include <math.h>

#define Bb 4
#define Nn 20480
#define Cc 128
#define Hh 8
#define HDd 16
#define Ll 4
#define NWw 320
#define WSs 64
#define BN 81920   // Bb*Nn

typedef short sv8 __attribute__((ext_vector_type(8)));
typedef __bf16 bfv8 __attribute__((ext_vector_type(8)));
typedef float f32x4 __attribute__((ext_vector_type(4)));

__device__ __forceinline__ f32x4 mfma16(sv8 a, sv8 b, f32x4 c) {
    return __builtin_amdgcn_mfma_f32_16x16x32_bf16(
        __builtin_bit_cast(bfv8, a), __builtin_bit_cast(bfv8, b), c, 0, 0, 0);
}

__device__ __forceinline__ ushort f2bf(float f) {
    uint u = __float_as_uint(f);
    u += 0x7fffu + ((u >> 16) & 1u);
    return (ushort)(u >> 16);
}
__device__ __forceinline__ float gelu_f(float x) {
    return 0.5f * x * (1.f + tanhf(0.7978845608f * (x + 0.044715f * x * x * x)));
}

// ---------------- sort_idx: stable argsort of window_ids (one wave per window)
__global__ __launch_bounds__(256) void sortidx_kernel(const int* __restrict__ wid,
                                                      int* __restrict__ sidx) {
    int wave = threadIdx.x >> 6, lane = threadIdx.x & 63;
    int w = blockIdx.x * 4 + wave;                // 0..319
    int base = 0;
    for (int i0 = 0; i0 < Nn; i0 += 64) {
        int id = wid[i0 + lane];
        unsigned long long mask = __ballot(id == w);
        if (id == w) {
            int pos = base + __popcll(mask & ((1ull << lane) - 1ull));
            sidx[w * WSs + pos] = i0 + lane;
        }
        base += __popcll(mask);
    }
}

// ---------------- weight convert + transpose to bf16 [N][K]
__global__ __launch_bounds__(256) void wconv_kernel(
    const float* __restrict__ Wqkv, const float* __restrict__ Wproj,
    const float* __restrict__ W1, const float* __restrict__ W2,
    ushort* __restrict__ wt) {
    int id = blockIdx.x * 256 + threadIdx.x;      // < 786432
    int l = id / 196608;
    int r = id % 196608;
    const float* src; int dst;
    if (r < 49152) { int n = r % 384, k = r / 384;
        src = Wqkv + l * 49152 + k * 384 + n; dst = l * 196608 + n * 128 + k; }
    else if (r < 65536) { int rr = r - 49152; int n = rr % 128, k = rr / 128;
        src = Wproj + l * 16384 + k * 128 + n; dst = l * 196608 + 49152 + n * 128 + k; }
    else if (r < 131072) { int rr = r - 65536; int n = rr % 512, k = rr / 512;
        src = W1 + l * 65536 + k * 512 + n; dst = l * 196608 + 65536 + n * 128 + k; }
    else { int rr = r - 131072; int n = rr % 128, k = rr / 128;
        src = W2 + l * 65536 + k * 128 + n; dst = l * 196608 + 131072 + n * 512 + k; }
    wt[dst] = f2bf(*src);
}

// ---------------- LayerNorm (optionally gathered by sort_idx), fp32 in -> bf16 out
__global__ __launch_bounds__(256) void ln_kernel(
    const float* __restrict__ xsrc, const float* __restrict__ g,
    const float* __restrict__ be, const int* __restrict__ sidx,
    ushort* __restrict__ h, int gather) {
    int wave = threadIdx.x >> 6, lane = threadIdx.x & 63;
    int row = blockIdx.x * 4 + wave;              // sorted-domain row 0..81919
    int b = row / Nn, p = row % Nn;
    int i = gather ? sidx[p] : p;
    const float* xr = xsrc + ((size_t)b * Nn + i) * Cc;
    float2 v = *(const float2*)(xr + lane * 2);
    float s = v.x + v.y;
    s += __shfl_xor(s, 1, 64);  s += __shfl_xor(s, 2, 64);
    s += __shfl_xor(s, 4, 64);  s += __shfl_xor(s, 8, 64);
    s += __shfl_xor(s, 16, 64); s += __shfl_xor(s, 32, 64);
    float mu = s * (1.f / 128.f);
    float dx = v.x - mu, dy = v.y - mu;
    float q = dx * dx + dy * dy;
    q += __shfl_xor(q, 1, 64);  q += __shfl_xor(q, 2, 64);
    q += __shfl_xor(q, 4, 64);  q += __shfl_xor(q, 8, 64);
    q += __shfl_xor(q, 16, 64); q += __shfl_xor(q, 32, 64);
    float rs = rsqrtf(q * (1.f / 128.f) + 1e-5f);
    float2 gg = *(const float2*)(g + lane * 2);
    float2 bb = *(const float2*)(be + lane * 2);
    float o0 = dx * rs * gg.x + bb.x;
    float o1 = dy * rs * gg.y + bb.y;
    uint pk = (uint)f2bf(o0) | ((uint)f2bf(o1) << 16);
    *(uint*)(h + (size_t)row * Cc + lane * 2) = pk;
}

// ---------------- GEMM: out[M][N] = A[M][K] @ BT[N][K]^T + bias, various epilogues
// MODE 0: store bf16. 1: gelu->bf16. 2: residual+scatter(sort_idx) fp32. 3: residual fp32.
template <int MODE, int KK>
__global__ __launch_bounds__(256) void gemm_kernel(
    const ushort* __restrict__ A, const ushort* __restrict__ BT,
    const float* __restrict__ bias, ushort* __restrict__ outb,
    float* __restrict__ dst, const float* __restrict__ res,
    const int* __restrict__ sidx, int N) {
    int wave = threadIdx.x >> 6, lane = threadIdx.x & 63;
    int rbase = blockIdx.x * 256 + wave * 64;
    int nbase = blockIdx.y * 64;
    int lr = lane & 15, lg = lane >> 4;
    f32x4 acc[4][4] = {};
    #pragma unroll
    for (int ks = 0; ks < KK / 32; ++ks) {
        int k0 = ks * 32 + lg * 8;
        sv8 a[4], b[4];
        #pragma unroll
        for (int rf = 0; rf < 4; ++rf)
            a[rf] = *(const sv8*)(A + (size_t)(rbase + rf * 16 + lr) * KK + k0);
        #pragma unroll
        for (int nf = 0; nf < 4; ++nf)
            b[nf] = *(const sv8*)(BT + (size_t)(nbase + nf * 16 + lr) * KK + k0);
        #pragma unroll
        for (int rf = 0; rf < 4; ++rf)
            #pragma unroll
            for (int nf = 0; nf < 4; ++nf)
                acc[rf][nf] = mfma16(a[rf], b[nf], acc[rf][nf]);
    }
    #pragma unroll
    for (int rf = 0; rf < 4; ++rf) {
        int row0 = rbase + rf * 16 + lg * 4;
        #pragma unroll
        for (int nf = 0; nf < 4; ++nf) {
            int col = nbase + nf * 16 + lr;
            float bs = bias[col];
            #pragma unroll
            for (int r = 0; r < 4; ++r) {
                float v = acc[rf][nf][r] + bs;
                int m = row0 + r;
                if (MODE == 0) {
                    outb[(size_t)m * N + col] = f2bf(v);
                } else if (MODE == 1) {
                    outb[(size_t)m * N + col] = f2bf(gelu_f(v));
                } else if (MODE == 2) {
                    int bidx = m / Nn, p = m % Nn;
                    int i = sidx[p];
                    size_t a_ = ((size_t)bidx * Nn + i) * Cc + col;
                    dst[a_] = res[a_] + v;
                } else {
                    size_t a_ = (size_t)m * Cc + col;
                    dst[a_] = res[a_] + v;
                }
            }
        }
    }
}

// ---------------- attention: one wave per (window, head)
__global__ __launch_bounds__(256) void attn_kernel(
    const ushort* __restrict__ qkv,   // [81920][384] bf16, sorted order
    const float* __restrict__ rb_ptr, // [8] this layer
    ushort* __restrict__ out) {       // [81920][128] bf16
    __shared__ __align__(16) ushort pt[4][64][80];
    int wave = threadIdx.x >> 6, lane = threadIdx.x & 63;
    int id = blockIdx.x * 4 + wave;
    int win = id >> 3, hh = id & 7;
    int lr = lane & 15, lg = lane >> 4;
    float rb = rb_ptr[hh];
    size_t base = (size_t)win * 64 * 384;

    // Q/K fragments: K-dim padded 16->32, lanes with lg>=2 hold zeros
    sv8 aq[4], bk[4];
    sv8 z = {0, 0, 0, 0, 0, 0, 0, 0};
    bool lo = (lg < 2);
    #pragma unroll
    for (int f = 0; f < 4; ++f) {
        aq[f] = z; bk[f] = z;
        if (lo) {
            aq[f] = *(const sv8*)(qkv + base + (size_t)(f * 16 + lr) * 384 + hh * 16 + lg * 8);
            bk[f] = *(const sv8*)(qkv + base + (size_t)(f * 16 + lr) * 384 + 128 + hh * 16 + lg * 8);
        }
    }
    f32x4 zz = {0.f, 0.f, 0.f, 0.f};
    f32x4 s[4][4];
    #pragma unroll
    for (int rf = 0; rf < 4; ++rf)
        #pragma unroll
        for (int nf = 0; nf < 4; ++nf)
            s[rf][nf] = mfma16(aq[rf], bk[nf], zz);

    // softmax over cols (keys); row = rf*16 + lg*4 + r, col = nf*16 + lr
    #pragma unroll
    for (int rf = 0; rf < 4; ++rf)
        #pragma unroll
        for (int r = 0; r < 4; ++r) {
            float mx = -1e30f;
            #pragma unroll
            for (int nf = 0; nf < 4; ++nf) {
                float v = s[rf][nf][r] * 0.25f + rb;
                s[rf][nf][r] = v;
                mx = fmaxf(mx, v);
            }
            mx = fmaxf(mx, __shfl_xor(mx, 1, 64));
            mx = fmaxf(mx, __shfl_xor(mx, 2, 64));
            mx = fmaxf(mx, __shfl_xor(mx, 4, 64));
            mx = fmaxf(mx, __shfl_xor(mx, 8, 64));
            float sum = 0.f;
            #pragma unroll
            for (int nf = 0; nf < 4; ++nf) {
                float e = expf(s[rf][nf][r] - mx);
                s[rf][nf][r] = e;
                sum += e;
            }
            sum += __shfl_xor(sum, 1, 64);
            sum += __shfl_xor(sum, 2, 64);
            sum += __shfl_xor(sum, 4, 64);
            sum += __shfl_xor(sum, 8, 64);
            float inv = 1.f / sum;
            int row = rf * 16 + lg * 4 + r;
            #pragma unroll
            for (int nf = 0; nf < 4; ++nf)
                pt[wave][row][nf * 16 + lr] = f2bf(s[rf][nf][r] * inv);
        }

    // PV: A = P (from LDS, transposed layout), B = V, K = 64 in 2 steps
    sv8 ap[4][2];
    #pragma unroll
    for (int rf = 0; rf < 4; ++rf)
        #pragma unroll
        for (int ks = 0; ks < 2; ++ks)
            ap[rf][ks] = *(const sv8*)&pt[wave][rf * 16 + lr][ks * 32 + lg * 8];

    sv8 bv[2];
    #pragma unroll
    for (int ks = 0; ks < 2; ++ks)
        #pragma unroll
        for (int j = 0; j < 8; ++j) {
            int k = ks * 32 + lg * 8 + j;
            bv[ks][j] = (short)qkv[base + (size_t)k * 384 + 256 + hh * 16 + lr];
        }

    f32x4 o[4];
    #pragma unroll
    for (int rf = 0; rf < 4; ++rf) {
        o[rf] = zz;
        #pragma unroll
        for (int ks = 0; ks < 2; ++ks)
            o[rf] = mfma16(ap[rf][ks], bv[ks], o[rf]);
    }
    #pragma unroll
    for (int rf = 0; rf < 4; ++rf)
        #pragma unroll
        for (int r = 0; r < 4; ++r) {
            int row = rf * 16 + lg * 4 + r;
            out[((size_t)win * 64 + row) * Cc + hh * 16 + lr] = f2bf(o[rf][r]);
        }
}

extern "C" void kernel_launch(void* const* d_in, const int* in_sizes, int n_in,
                              void* d_out, int out_size, void* d_ws, size_t ws_size,
                              hipStream_t stream) {
    const float* x_in   = (const float*)d_in[0];
    const float* g1     = (const float*)d_in[1];
    const float* be1    = (const float*)d_in[2];
    const float* Wqkv   = (const float*)d_in[3];
    const float* bqkv   = (const float*)d_in[4];
    const float* relb   = (const float*)d_in[5];
    const float* Wproj  = (const float*)d_in[6];
    const float* bproj  = (const float*)d_in[7];
    const float* g2     = (const float*)d_in[8];
    const float* be2    = (const float*)d_in[9];
    const float* W1     = (const float*)d_in[10];
    const float* b1     = (const float*)d_in[11];
    const float* W2     = (const float*)d_in[12];
    const float* b2     = (const float*)d_in[13];
    const int*   wid    = (const int*)d_in[14];

    // ws layout
    size_t off = 0;
    float* x_ws = (float*)d_ws;                         off += (size_t)BN * Cc * 4;   // 41.9 MB
    ushort* h_ws = (ushort*)((char*)d_ws + off);        off += (size_t)BN * Cc * 2;   // 21.0 MB (h / attn_out)
    ushort* big_ws = (ushort*)((char*)d_ws + off);      off += (size_t)BN * 512 * 2;  // 83.9 MB (qkv / mlp hidden)
    ushort* wt_ws = (ushort*)((char*)d_ws + off);       off += (size_t)786432 * 2;    // 1.6 MB
    int* sidx = (int*)((char*)d_ws + off);              off += (size_t)Nn * 4;
    if (ws_size < off) return;

    sortidx_kernel<<<NWw / 4, 256, 0, stream>>>(wid, sidx);
    wconv_kernel<<<786432 / 256, 256, 0, stream>>>(Wqkv, Wproj, W1, W2, wt_ws);

    for (int l = 0; l < Ll; ++l) {
        const float* xsrc = (l == 0) ? x_in : x_ws;
        const ushort* wqkvT = wt_ws + (size_t)l * 196608;
        const ushort* wprojT = wqkvT + 49152;
        const ushort* w1T = wqkvT + 65536;
        const ushort* w2T = wqkvT + 131072;

        // gather + LN1 -> h (sorted order, bf16)
        ln_kernel<<<BN / 4, 256, 0, stream>>>(xsrc, g1 + l * Cc, be1 + l * Cc, sidx, h_ws, 1);
        // QKV
        gemm_kernel<0, 128><<<dim3(BN / 256, 6), 256, 0, stream>>>(
            h_ws, wqkvT, bqkv + l * 384, big_ws, nullptr, nullptr, nullptr, 384);
        // attention (writes into h_ws, sorted order)
        attn_kernel<<<(BN / WSs) * Hh / 4, 256, 0, stream>>>(big_ws, relb + l * Hh, h_ws);
        // proj + scatter residual -> x_ws
        gemm_kernel<2, 128><<<dim3(BN / 256, 2), 256, 0, stream>>>(
            h_ws, wprojT, bproj + l * Cc, nullptr, x_ws, xsrc, sidx, Cc);
        // LN2 -> h
        ln_kernel<<<BN / 4, 256, 0, stream>>>(x_ws, g2 + l * Cc, be2 + l * Cc, nullptr, h_ws, 0);
        // MLP1 + gelu -> big
        gemm_kernel<1, 128><<<dim3(BN / 256, 8), 256, 0, stream>>>(
            h_ws, w1T, b1 + l * 512, big_ws, nullptr, nullptr, nullptr, 512);
        // MLP2 + residual -> x (last layer -> d_out)
        float* xdst = (l == Ll - 1) ? (float*)d_out : x_ws;
        gemm_kernel<3, 512><<<dim3(BN / 256, 2), 256, 0, stream>>>(
            big_ws, w2T, b2 + l * Cc, nullptr, xdst, x_ws, nullptr, Cc);
    }
}

// Round 2
// 524.081 us; speedup vs baseline: 2.2183x; 2.2183x over previous
//
#include <hip/hip_runtime.h>
#include <hip/hip_bf16.h>
#include <math.h>

#define Nn 20480
#define Cc 128
#define Hh 8
#define Ll 4
#define NWw 320
#define BN 81920   // B*N

typedef short sv8 __attribute__((ext_vector_type(8)));
typedef __bf16 bfv8 __attribute__((ext_vector_type(8)));
typedef float f32x4 __attribute__((ext_vector_type(4)));

__device__ __forceinline__ f32x4 mfma16(sv8 a, sv8 b, f32x4 c) {
    return __builtin_amdgcn_mfma_f32_16x16x32_bf16(
        __builtin_bit_cast(bfv8, a), __builtin_bit_cast(bfv8, b), c, 0, 0, 0);
}
__device__ __forceinline__ ushort f2bf(float f) {
    uint u = __float_as_uint(f);
    u += 0x7fffu + ((u >> 16) & 1u);
    return (ushort)(u >> 16);
}
__device__ __forceinline__ float fast_gelu(float x) {
    float z = 0.7978845608f * (x + 0.044715f * x * x * x);
    return x * __builtin_amdgcn_rcpf(1.0f + __expf(-2.0f * z));
}

// ---------- stable counting sort of window_ids: 3 tiny kernels ----------
__global__ __launch_bounds__(64) void rank_kernel(const int* __restrict__ wid,
        int* __restrict__ lrank, int* __restrict__ hist) {
    __shared__ int keys[64];
    int c = blockIdx.x, lane = threadIdx.x;
    for (int j = lane; j < NWw; j += 64) hist[c * NWw + j] = 0;
    int i = c * 64 + lane;
    int w = wid[i];
    keys[lane] = w;
    __syncthreads();
    int rank = 0, total = 0;
    for (int j = 0; j < 64; ++j) {
        int kj = keys[j];
        total += (kj == w);
        rank += (j < lane && kj == w) ? 1 : 0;
    }
    lrank[i] = rank;
    if (rank == 0) hist[c * NWw + w] = total;
}
__global__ __launch_bounds__(64) void prefix_kernel(int* __restrict__ hist) {
    int w = blockIdx.x, lane = threadIdx.x;
    int running = 0;
    for (int it = 0; it < NWw / 64; ++it) {
        int c = it * 64 + lane;
        int v = hist[c * NWw + w];
        int orig = v;
        #pragma unroll
        for (int d = 1; d < 64; d <<= 1) {
            int tt = __shfl_up(v, d, 64);
            if (lane >= d) v += tt;
        }
        hist[c * NWw + w] = running + v - orig;
        running += __shfl(v, 63, 64);
    }
}
__global__ __launch_bounds__(64) void scatter_kernel(const int* __restrict__ wid,
        const int* __restrict__ lrank, const int* __restrict__ hist,
        int* __restrict__ sidx) {
    int c = blockIdx.x, lane = threadIdx.x;
    int i = c * 64 + lane;
    int w = wid[i];
    sidx[w * 64 + hist[c * NWw + w] + lrank[i]] = i;
}

// ---------- weight convert + transpose to bf16 [N][K] ----------
__global__ __launch_bounds__(256) void wconv_kernel(
    const float* __restrict__ Wqkv, const float* __restrict__ Wproj,
    const float* __restrict__ W1, const float* __restrict__ W2,
    ushort* __restrict__ wt) {
    int id = blockIdx.x * 256 + threadIdx.x;      // < 786432
    int l = id / 196608;
    int r = id % 196608;
    const float* src; int dst;
    if (r < 49152) { int n = r % 384, k = r / 384;
        src = Wqkv + l * 49152 + k * 384 + n; dst = l * 196608 + n * 128 + k; }
    else if (r < 65536) { int rr = r - 49152; int n = rr % 128, k = rr / 128;
        src = Wproj + l * 16384 + k * 128 + n; dst = l * 196608 + 49152 + n * 128 + k; }
    else if (r < 131072) { int rr = r - 65536; int n = rr % 512, k = rr / 512;
        src = W1 + l * 65536 + k * 512 + n; dst = l * 196608 + 65536 + n * 128 + k; }
    else { int rr = r - 131072; int n = rr % 128, k = rr / 128;
        src = W2 + l * 65536 + k * 128 + n; dst = l * 196608 + 131072 + n * 512 + k; }
    wt[dst] = f2bf(*src);
}

// ---------- fused attention block: gather+LN1 -> QKV -> attn -> proj+residual ----------
// one block per (batch, window): 256 threads / 4 waves, 64 tokens
__global__ __launch_bounds__(256, 2) void attn_fused_kernel(
    const float* __restrict__ xsrc, float* __restrict__ xdst,
    const ushort* __restrict__ wqkvT, const float* __restrict__ bqkv,
    const float* __restrict__ relb, const ushort* __restrict__ wprojT,
    const float* __restrict__ bproj, const float* __restrict__ g1,
    const float* __restrict__ be1, const int* __restrict__ sidx) {
    __shared__ __align__(16) ushort hl_[64][128];   // LN out; reused as attn-out
    __shared__ __align__(16) ushort qk_[64][384];   // q|k|v
    __shared__ __align__(16) ushort pt[4][16][88];  // P subtile per wave
    __shared__ int ridx[64];

    int t = threadIdx.x;
    int wave = t >> 6, lane = t & 63;
    int lr = lane & 15, lg = lane >> 4;
    int wb = blockIdx.x;
    int bN = (wb / NWw) * Nn;
    int p0 = (wb % NWw) * 64;

    if (t < 64) ridx[t] = sidx[p0 + t];
    __syncthreads();

    // ---- phase 1: gather + LN1 -> hl_ (bf16, swizzled)
    {
        int hl2 = lane & 31, hb = lane >> 5;
        float4 gg = *(const float4*)(g1 + hl2 * 4);
        float4 bb = *(const float4*)(be1 + hl2 * 4);
        #pragma unroll
        for (int it = 0; it < 8; ++it) {
            int row = it * 8 + wave * 2 + hb;
            int gi = bN + ridx[row];
            float4 v = *(const float4*)(xsrc + (size_t)gi * Cc + hl2 * 4);
            float s = v.x + v.y + v.z + v.w;
            s += __shfl_xor(s, 1, 64);  s += __shfl_xor(s, 2, 64);
            s += __shfl_xor(s, 4, 64);  s += __shfl_xor(s, 8, 64);
            s += __shfl_xor(s, 16, 64);
            float mu = s * 0.0078125f;
            float d0 = v.x - mu, d1 = v.y - mu, d2 = v.z - mu, d3 = v.w - mu;
            float q = d0 * d0 + d1 * d1 + d2 * d2 + d3 * d3;
            q += __shfl_xor(q, 1, 64);  q += __shfl_xor(q, 2, 64);
            q += __shfl_xor(q, 4, 64);  q += __shfl_xor(q, 8, 64);
            q += __shfl_xor(q, 16, 64);
            float rs = rsqrtf(q * 0.0078125f + 1e-5f);
            uint2 pk;
            pk.x = (uint)f2bf(d0 * rs * gg.x + bb.x) | ((uint)f2bf(d1 * rs * gg.y + bb.y) << 16);
            pk.y = (uint)f2bf(d2 * rs * gg.z + bb.z) | ((uint)f2bf(d3 * rs * gg.w + bb.w) << 16);
            *(uint2*)&hl_[row][(hl2 * 4) ^ ((row & 7) << 3)] = pk;
        }
    }
    __syncthreads();

    // ---- phase 2: QKV GEMM (wave -> 96 cols), write qk_ LDS
    {
        f32x4 acc[4][6] = {};
        #pragma unroll
        for (int ks = 0; ks < 4; ++ks) {
            int k0 = ks * 32 + lg * 8;
            sv8 a[4], b[6];
            #pragma unroll
            for (int rf = 0; rf < 4; ++rf) {
                int row = rf * 16 + lr;
                a[rf] = *(const sv8*)&hl_[row][k0 ^ ((row & 7) << 3)];
            }
            #pragma unroll
            for (int nf = 0; nf < 6; ++nf)
                b[nf] = *(const sv8*)(wqkvT + (size_t)(wave * 96 + nf * 16 + lr) * 128 + k0);
            #pragma unroll
            for (int rf = 0; rf < 4; ++rf)
                #pragma unroll
                for (int nf = 0; nf < 6; ++nf)
                    acc[rf][nf] = mfma16(a[rf], b[nf], acc[rf][nf]);
        }
        #pragma unroll
        for (int nf = 0; nf < 6; ++nf) {
            int col = wave * 96 + nf * 16 + lr;
            float bs = bqkv[col];
            #pragma unroll
            for (int rf = 0; rf < 4; ++rf)
                #pragma unroll
                for (int r = 0; r < 4; ++r) {
                    int row = rf * 16 + lg * 4 + r;
                    qk_[row][col ^ ((row & 7) << 3)] = f2bf(acc[rf][nf][r] + bs);
                }
        }
    }
    __syncthreads();   // qk_ ready; hl_ reads done -> safe to overwrite as attn-out

    // ---- phase 3: attention, 2 heads per wave
    f32x4 zz = {0.f, 0.f, 0.f, 0.f};
    #pragma unroll
    for (int hi = 0; hi < 2; ++hi) {
        int hh = wave * 2 + hi;
        float rb = relb[hh];
        // V fragments (strided scalar LDS reads)
        sv8 bv[2];
        #pragma unroll
        for (int ks = 0; ks < 2; ++ks)
            #pragma unroll
            for (int j = 0; j < 8; ++j) {
                int k = ks * 32 + lg * 8 + j;
                int e = 256 + hh * 16 + lr;
                bv[ks][j] = (short)qk_[k][e ^ ((k & 7) << 3)];
            }
        // Q/K fragments, K-dim padded 16->32 (lg>=2 zero)
        sv8 aq[4], bk[4];
        sv8 z = {0, 0, 0, 0, 0, 0, 0, 0};
        bool lo = (lg < 2);
        #pragma unroll
        for (int f = 0; f < 4; ++f) {
            aq[f] = z; bk[f] = z;
            if (lo) {
                int row = f * 16 + lr;
                int eq = hh * 16 + lg * 8;
                aq[f] = *(const sv8*)&qk_[row][eq ^ ((row & 7) << 3)];
                int ek = 128 + hh * 16 + lg * 8;
                bk[f] = *(const sv8*)&qk_[row][ek ^ ((row & 7) << 3)];
            }
        }
        f32x4 s[4][4];
        #pragma unroll
        for (int rf = 0; rf < 4; ++rf)
            #pragma unroll
            for (int nf = 0; nf < 4; ++nf)
                s[rf][nf] = mfma16(aq[rf], bk[nf], zz);

        f32x4 o[4];
        #pragma unroll
        for (int rf = 0; rf < 4; ++rf) {
            #pragma unroll
            for (int r = 0; r < 4; ++r) {
                float vv[4];
                float mx = -1e30f;
                #pragma unroll
                for (int nf = 0; nf < 4; ++nf) {
                    float v = s[rf][nf][r] * 0.25f + rb;
                    vv[nf] = v;
                    mx = fmaxf(mx, v);
                }
                mx = fmaxf(mx, __shfl_xor(mx, 1, 64));
                mx = fmaxf(mx, __shfl_xor(mx, 2, 64));
                mx = fmaxf(mx, __shfl_xor(mx, 4, 64));
                mx = fmaxf(mx, __shfl_xor(mx, 8, 64));
                float sum = 0.f;
                #pragma unroll
                for (int nf = 0; nf < 4; ++nf) {
                    float e = __expf(vv[nf] - mx);
                    vv[nf] = e;
                    sum += e;
                }
                sum += __shfl_xor(sum, 1, 64);
                sum += __shfl_xor(sum, 2, 64);
                sum += __shfl_xor(sum, 4, 64);
                sum += __shfl_xor(sum, 8, 64);
                float inv = __builtin_amdgcn_rcpf(sum);
                #pragma unroll
                for (int nf = 0; nf < 4; ++nf)
                    pt[wave][lg * 4 + r][nf * 16 + lr] = f2bf(vv[nf] * inv);
            }
            sv8 ap0 = *(const sv8*)&pt[wave][lr][lg * 8];
            sv8 ap1 = *(const sv8*)&pt[wave][lr][32 + lg * 8];
            o[rf] = mfma16(ap0, bv[0], zz);
            o[rf] = mfma16(ap1, bv[1], o[rf]);
        }
        #pragma unroll
        for (int rf = 0; rf < 4; ++rf)
            #pragma unroll
            for (int r = 0; r < 4; ++r) {
                int row = rf * 16 + lg * 4 + r;
                int e = hh * 16 + lr;
                hl_[row][e ^ ((row & 7) << 3)] = f2bf(o[rf][r]);
            }
    }
    __syncthreads();

    // ---- phase 4: proj + bias + residual, scatter to original rows
    {
        f32x4 acc[4][2] = {};
        #pragma unroll
        for (int ks = 0; ks < 4; ++ks) {
            int k0 = ks * 32 + lg * 8;
            sv8 a[4], b[2];
            #pragma unroll
            for (int rf = 0; rf < 4; ++rf) {
                int row = rf * 16 + lr;
                a[rf] = *(const sv8*)&hl_[row][k0 ^ ((row & 7) << 3)];
            }
            #pragma unroll
            for (int nf = 0; nf < 2; ++nf)
                b[nf] = *(const sv8*)(wprojT + (size_t)(wave * 32 + nf * 16 + lr) * 128 + k0);
            #pragma unroll
            for (int rf = 0; rf < 4; ++rf)
                #pragma unroll
                for (int nf = 0; nf < 2; ++nf)
                    acc[rf][nf] = mfma16(a[rf], b[nf], acc[rf][nf]);
        }
        #pragma unroll
        for (int nf = 0; nf < 2; ++nf) {
            int col = wave * 32 + nf * 16 + lr;
            float bs = bproj[col];
            #pragma unroll
            for (int rf = 0; rf < 4; ++rf)
                #pragma unroll
                for (int r = 0; r < 4; ++r) {
                    int row = rf * 16 + lg * 4 + r;
                    int gi = bN + ridx[row];
                    size_t ad = (size_t)gi * Cc + col;
                    xdst[ad] = xsrc[ad] + acc[rf][nf][r] + bs;
                }
        }
    }
}

// ---------- fused MLP block: LN2 -> MLP1+GELU -> MLP2+residual ----------
__global__ __launch_bounds__(256, 2) void mlp_fused_kernel(
    const float* __restrict__ xsrc, float* __restrict__ xdst,
    const ushort* __restrict__ w1T, const float* __restrict__ b1,
    const ushort* __restrict__ w2T, const float* __restrict__ b2,
    const float* __restrict__ g2, const float* __restrict__ be2) {
    __shared__ __align__(16) ushort hl_[64][128];
    __shared__ __align__(16) ushort hid[64][512];
    int t = threadIdx.x, wave = t >> 6, lane = t & 63;
    int lr = lane & 15, lg = lane >> 4;
    int r0 = blockIdx.x * 64;

    // phase 1: LN2
    {
        int hl2 = lane & 31, hb = lane >> 5;
        float4 gg = *(const float4*)(g2 + hl2 * 4);
        float4 bb = *(const float4*)(be2 + hl2 * 4);
        #pragma unroll
        for (int it = 0; it < 8; ++it) {
            int row = it * 8 + wave * 2 + hb;
            float4 v = *(const float4*)(xsrc + (size_t)(r0 + row) * Cc + hl2 * 4);
            float s = v.x + v.y + v.z + v.w;
            s += __shfl_xor(s, 1, 64);  s += __shfl_xor(s, 2, 64);
            s += __shfl_xor(s, 4, 64);  s += __shfl_xor(s, 8, 64);
            s += __shfl_xor(s, 16, 64);
            float mu = s * 0.0078125f;
            float d0 = v.x - mu, d1 = v.y - mu, d2 = v.z - mu, d3 = v.w - mu;
            float q = d0 * d0 + d1 * d1 + d2 * d2 + d3 * d3;
            q += __shfl_xor(q, 1, 64);  q += __shfl_xor(q, 2, 64);
            q += __shfl_xor(q, 4, 64);  q += __shfl_xor(q, 8, 64);
            q += __shfl_xor(q, 16, 64);
            float rs = rsqrtf(q * 0.0078125f + 1e-5f);
            uint2 pk;
            pk.x = (uint)f2bf(d0 * rs * gg.x + bb.x) | ((uint)f2bf(d1 * rs * gg.y + bb.y) << 16);
            pk.y = (uint)f2bf(d2 * rs * gg.z + bb.z) | ((uint)f2bf(d3 * rs * gg.w + bb.w) << 16);
            *(uint2*)&hl_[row][(hl2 * 4) ^ ((row & 7) << 3)] = pk;
        }
    }
    __syncthreads();

    // phase 2: MLP1 + gelu -> hid (wave -> 128 cols)
    {
        f32x4 acc[4][8] = {};
        #pragma unroll
        for (int ks = 0; ks < 4; ++ks) {
            int k0 = ks * 32 + lg * 8;
            sv8 a[4], b[8];
            #pragma unroll
            for (int rf = 0; rf < 4; ++rf) {
                int row = rf * 16 + lr;
                a[rf] = *(const sv8*)&hl_[row][k0 ^ ((row & 7) << 3)];
            }
            #pragma unroll
            for (int nf = 0; nf < 8; ++nf)
                b[nf] = *(const sv8*)(w1T + (size_t)(wave * 128 + nf * 16 + lr) * 128 + k0);
            #pragma unroll
            for (int rf = 0; rf < 4; ++rf)
                #pragma unroll
                for (int nf = 0; nf < 8; ++nf)
                    acc[rf][nf] = mfma16(a[rf], b[nf], acc[rf][nf]);
        }
        #pragma unroll
        for (int nf = 0; nf < 8; ++nf) {
            int col = wave * 128 + nf * 16 + lr;
            float bs = b1[col];
            #pragma unroll
            for (int rf = 0; rf < 4; ++rf)
                #pragma unroll
                for (int r = 0; r < 4; ++r) {
                    int row = rf * 16 + lg * 4 + r;
                    hid[row][col ^ ((row & 7) << 3)] = f2bf(fast_gelu(acc[rf][nf][r] + bs));
                }
        }
    }
    __syncthreads();

    // phase 3: MLP2 + bias + residual (wave -> 32 cols, K=512)
    {
        f32x4 acc[4][2] = {};
        #pragma unroll
        for (int ks = 0; ks < 16; ++ks) {
            int k0 = ks * 32 + lg * 8;
            sv8 a[4], b[2];
            #pragma unroll
            for (int rf = 0; rf < 4; ++rf) {
                int row = rf * 16 + lr;
                a[rf] = *(const sv8*)&hid[row][k0 ^ ((row & 7) << 3)];
            }
            #pragma unroll
            for (int nf = 0; nf < 2; ++nf)
                b[nf] = *(const sv8*)(w2T + (size_t)(wave * 32 + nf * 16 + lr) * 512 + k0);
            #pragma unroll
            for (int rf = 0; rf < 4; ++rf)
                #pragma unroll
                for (int nf = 0; nf < 2; ++nf)
                    acc[rf][nf] = mfma16(a[rf], b[nf], acc[rf][nf]);
        }
        #pragma unroll
        for (int nf = 0; nf < 2; ++nf) {
            int col = wave * 32 + nf * 16 + lr;
            float bs = b2[col];
            #pragma unroll
            for (int rf = 0; rf < 4; ++rf)
                #pragma unroll
                for (int r = 0; r < 4; ++r) {
                    int row = rf * 16 + lg * 4 + r;
                    size_t ad = (size_t)(r0 + row) * Cc + col;
                    xdst[ad] = xsrc[ad] + acc[rf][nf][r] + bs;
                }
        }
    }
}

extern "C" void kernel_launch(void* const* d_in, const int* in_sizes, int n_in,
                              void* d_out, int out_size, void* d_ws, size_t ws_size,
                              hipStream_t stream) {
    const float* x_in   = (const float*)d_in[0];
    const float* g1     = (const float*)d_in[1];
    const float* be1    = (const float*)d_in[2];
    const float* Wqkv   = (const float*)d_in[3];
    const float* bqkv   = (const float*)d_in[4];
    const float* relb   = (const float*)d_in[5];
    const float* Wproj  = (const float*)d_in[6];
    const float* bproj  = (const float*)d_in[7];
    const float* g2     = (const float*)d_in[8];
    const float* be2    = (const float*)d_in[9];
    const float* W1     = (const float*)d_in[10];
    const float* b1     = (const float*)d_in[11];
    const float* W2     = (const float*)d_in[12];
    const float* b2     = (const float*)d_in[13];
    const int*   wid    = (const int*)d_in[14];

    size_t off = 0;
    float* x_ws = (float*)d_ws;                      off += (size_t)BN * Cc * 4;
    ushort* wt  = (ushort*)((char*)d_ws + off);      off += (size_t)786432 * 2;
    int* sidx   = (int*)((char*)d_ws + off);         off += (size_t)Nn * 4;
    int* lrank  = (int*)((char*)d_ws + off);         off += (size_t)Nn * 4;
    int* hist   = (int*)((char*)d_ws + off);         off += (size_t)NWw * NWw * 4;
    if (ws_size < off) return;

    rank_kernel<<<Nn / 64, 64, 0, stream>>>(wid, lrank, hist);
    prefix_kernel<<<NWw, 64, 0, stream>>>(hist);
    scatter_kernel<<<Nn / 64, 64, 0, stream>>>(wid, lrank, hist, sidx);
    wconv_kernel<<<786432 / 256, 256, 0, stream>>>(Wqkv, Wproj, W1, W2, wt);

    for (int l = 0; l < Ll; ++l) {
        const ushort* wqkvT  = wt + (size_t)l * 196608;
        const ushort* wprojT = wqkvT + 49152;
        const ushort* w1T    = wqkvT + 65536;
        const ushort* w2T    = wqkvT + 131072;
        const float* xsrc = (l == 0) ? x_in : x_ws;

        attn_fused_kernel<<<BN / 64, 256, 0, stream>>>(
            xsrc, x_ws, wqkvT, bqkv + l * 384, relb + l * Hh,
            wprojT, bproj + l * Cc, g1 + l * Cc, be1 + l * Cc, sidx);

        float* xdst = (l == Ll - 1) ? (float*)d_out : x_ws;
        mlp_fused_kernel<<<BN / 64, 256, 0, stream>>>(
            x_ws, xdst, w1T, b1 + l * 512, w2T, b2 + l * Cc,
            g2 + l * Cc, be2 + l * Cc);
    }
}